// Round 8
// baseline (148.768 us; speedup 1.0000x reference)
//
#include <hip/hip_runtime.h>
#include <hip/hip_bf16.h>
#include <string.h>

#define NTOK 64
#define HEADS 8

typedef __attribute__((ext_vector_type(4))) float f32x4;
typedef __attribute__((ext_vector_type(2))) unsigned int u32x2;
typedef __attribute__((ext_vector_type(4))) unsigned int u32x4;
typedef __attribute__((ext_vector_type(8))) short bf16x8;

__device__ float g_bias225[225 * 8];   // overwritten fully every launch (deterministic)

// scalar f32 -> bf16 (RNE)
__device__ __forceinline__ unsigned int f2bf(float f) {
    unsigned int u = __float_as_uint(f);
    u += 0x7FFFu + ((u >> 16) & 1u);
    return u >> 16;
}
// packed f32x2 -> bf16x2 (RNE) -- v_cvt_pk_bf16_f32
__device__ __forceinline__ unsigned int cvt2(float a, float b) {
    __hip_bfloat162 h = __float22bfloat162_rn(float2{a, b});
    unsigned int r;
    memcpy(&r, &h, 4);
    return r;
}

// Stage 1: MLP over the 225 distinct relative positions. One wave per pair.
__global__ __launch_bounds__(64) void mlp_pairs_kernel(
    const float* __restrict__ w1, const float* __restrict__ b1,
    const float* __restrict__ w2, const float* __restrict__ b2)
{
    int pair = blockIdx.x;
    int lane = threadIdx.x;
    int dy = pair / 15 - 7;
    int dx = pair % 15 - 7;
    float fy = copysignf(log1pf(fabsf((float)dy)), (float)dy);
    float fx = copysignf(log1pf(fabsf((float)dx)), (float)dx);
    int h = lane & 7;
    int j0 = lane >> 3;
    float acc = 0.0f;
    #pragma unroll 4
    for (int i = 0; i < 32; ++i) {
        int j = j0 + 8 * i;
        float t = fy * w1[j] + fx * w1[256 + j] + b1[j];
        float ge = 0.5f * t * (1.0f + erff(t * 0.70710678118654752f)); // exact GELU
        acc = fmaf(ge, w2[j * HEADS + h], acc);
    }
    acc += __shfl_xor(acc, 8, 64);
    acc += __shfl_xor(acc, 16, 64);
    acc += __shfl_xor(acc, 32, 64);
    if (lane < 8)
        g_bias225[pair * 8 + lane] = (acc + b2[lane]) * 1.44269504088896341f; // fold log2(e)
}

// Stage 2: scatter bias225 -> fragment-layout table
// bias_ws[h][mt][nt][lane][r] = log2e * bias[h][n][m],
//   m = mt*16 + (lane>>4)*4 + r (S^T C-frag row), n = nt*16 + (lane&15) (col)
__global__ __launch_bounds__(256) void bias_scatter_kernel(float* __restrict__ bias_ws)
{
    int idx = blockIdx.x * 256 + threadIdx.x;   // 32768 total
    int r  = idx & 3;
    int l  = (idx >> 2) & 63;
    int nt = (idx >> 8) & 3;
    int mt = (idx >> 10) & 3;
    int h  = idx >> 12;
    int n = nt * 16 + (l & 15);
    int m = mt * 16 + (l >> 4) * 4 + r;
    int pair = ((n >> 3) - (m >> 3) + 7) * 15 + ((n & 7) - (m & 7) + 7);
    bias_ws[idx] = g_bias225[pair * 8 + h];
}

// One wave per (window b, head h). 4 waves/block, fully independent (no barrier).
// Occupancy-max variant: LDS = P-dbuf only (18.4 KB/block); VGPR capped for 5 waves/SIMD.
__global__ __launch_bounds__(256, 5) void win_attn_kernel(
    const float* __restrict__ qkv,
    const float* __restrict__ bias_ws,
    float* __restrict__ out)
{
    __shared__ __align__(16) unsigned short lds_p[4][2][16][72]; // dbuf wave-private P slices
    const int w = threadIdx.x >> 6;
    const int l = threadIdx.x & 63;
    const int c = l & 15;
    const int g = l >> 4;
    const int W = blockIdx.x * 4 + w;
    const int h = W & 7;
    const int b = W >> 3;
    const float* base = qkv + (size_t)b * (NTOK * 768) + h * 32;
    const float QS = 0.176776695296636893f * 1.44269504088896341f; // scale * log2(e)

    // ---- K fragments direct from global (A-frag: own-row = c, k-chunk = g*8) ----
    bf16x8 kf[4];
    #pragma unroll
    for (int t = 0; t < 4; ++t) {
        const float* pk = base + (size_t)(t * 16 + c) * 768 + 256 + g * 8;
        f32x4 y0 = *(const f32x4*)(pk);
        f32x4 y1 = *(const f32x4*)(pk + 4);
        u32x4 kk = {cvt2(y0[0], y0[1]), cvt2(y0[2], y0[3]),
                    cvt2(y1[0], y1[1]), cvt2(y1[2], y1[3])};
        bf16x8 k;
        memcpy(&k, &kk, 16);
        kf[t] = k;
    }

    // ---- V^T A-fragments direct (lane: d = dt*16+c, k = m = ks*32 + g*8 + j) ----
    bf16x8 vf[2][2];
    {
        const float* vb = base + 512;
        #pragma unroll
        for (int ks = 0; ks < 2; ++ks)
            #pragma unroll
            for (int dt = 0; dt < 2; ++dt) {
                bf16x8 v;
                #pragma unroll
                for (int j = 0; j < 8; ++j)
                    v[j] = (short)f2bf(vb[(size_t)(ks * 32 + g * 8 + j) * 768 + dt * 16 + c]);
                vf[ks][dt] = v;
            }
    }

    // Q strip 0 raw
    f32x4 qraw0, qraw1;
    {
        const float* pq = base + (size_t)c * 768 + g * 8;
        qraw0 = *(const f32x4*)(pq);
        qraw1 = *(const f32x4*)(pq + 4);
    }

    float* ob = out + (size_t)b * (NTOK * 256) + h * 32;

    // ---- strip loop over n (nt): S^T strip -> exp2 -> P -> O^T strip ----
    #pragma unroll
    for (int nt = 0; nt < 4; ++nt) {
        bf16x8 qf;
        {
            u32x4 qq = {cvt2(qraw0[0] * QS, qraw0[1] * QS), cvt2(qraw0[2] * QS, qraw0[3] * QS),
                        cvt2(qraw1[0] * QS, qraw1[1] * QS), cvt2(qraw1[2] * QS, qraw1[3] * QS)};
            memcpy(&qf, &qq, 16);
        }

        // S^T strip = K.Q^T seeded with bias frags (C-operand; L2-resident table)
        f32x4 acc[4];
        {
            const f32x4* bw = (const f32x4*)(bias_ws) + ((size_t)h * 16 + nt) * 64 + l;
            #pragma unroll
            for (int mt = 0; mt < 4; ++mt)
                acc[mt] = bw[mt * 256];
        }
        #pragma unroll
        for (int mt = 0; mt < 4; ++mt)
            acc[mt] = __builtin_amdgcn_mfma_f32_16x16x32_bf16(kf[mt], qf, acc[mt], 0, 0, 0);

        // prefetch next strip's Q while MFMAs run
        if (nt < 3) {
            const float* pq = base + (size_t)((nt + 1) * 16 + c) * 768 + g * 8;
            qraw0 = *(const f32x4*)(pq);
            qraw1 = *(const f32x4*)(pq + 4);
        }

        // softmax numerators, no max-subtract (scores bounded in log2 units; f32-safe;
        // identical after normalization)
        float s = 0.0f;
        #pragma unroll
        for (int mt = 0; mt < 4; ++mt)
            #pragma unroll
            for (int r = 0; r < 4; ++r) {
                float p = __builtin_amdgcn_exp2f(acc[mt][r]);
                acc[mt][r] = p;
                s += p;
            }

        // P strip (bf16, [n][m]) -> LDS (packed cvt + b64 writes, double-buffered)
        unsigned short (*P)[72] = lds_p[w][nt & 1];
        #pragma unroll
        for (int mt = 0; mt < 4; ++mt) {
            unsigned int w0 = cvt2(acc[mt][0], acc[mt][1]);
            unsigned int w1 = cvt2(acc[mt][2], acc[mt][3]);
            *(u32x2*)(&P[c][mt * 16 + g * 4]) = (u32x2){w0, w1};
        }

        // cross-lane sum finish + rcp (overlaps the fence drain)
        s += __shfl_xor(s, 16, 64);
        s += __shfl_xor(s, 32, 64);
        float iv = __builtin_amdgcn_rcpf(s);

        // order: P ds_writes visible before cross-lane ds_reads
        __threadfence_block();

        // O^T strip = V^T . P^T
        f32x4 o[2];
        o[0] = (f32x4){0.f, 0.f, 0.f, 0.f};
        o[1] = (f32x4){0.f, 0.f, 0.f, 0.f};
        #pragma unroll
        for (int ks = 0; ks < 2; ++ks) {
            bf16x8 pb = *(const bf16x8*)(&P[c][ks * 32 + g * 8]);
            #pragma unroll
            for (int dt = 0; dt < 2; ++dt)
                o[dt] = __builtin_amdgcn_mfma_f32_16x16x32_bf16(vf[ks][dt], pb, o[dt], 0, 0, 0);
        }

        // normalize + store (4 consecutive d per reg -> dwordx4)
        #pragma unroll
        for (int dt = 0; dt < 2; ++dt) {
            f32x4 val;
            #pragma unroll
            for (int r = 0; r < 4; ++r)
                val[r] = o[dt][r] * iv;
            *(f32x4*)(ob + (size_t)(nt * 16 + c) * 256 + dt * 16 + g * 4) = val;
        }
    }
}

extern "C" void kernel_launch(void* const* d_in, const int* in_sizes, int n_in,
                              void* d_out, int out_size, void* d_ws, size_t ws_size,
                              hipStream_t stream) {
    const float* qkv = (const float*)d_in[0];
    const float* w1  = (const float*)d_in[1];
    const float* b1  = (const float*)d_in[2];
    const float* w2  = (const float*)d_in[3];
    const float* b2  = (const float*)d_in[4];
    float* bias_ws = (float*)d_ws;   // 32768 floats = 128 KiB (proven size)

    mlp_pairs_kernel<<<225, 64, 0, stream>>>(w1, b1, w2, b2);
    bias_scatter_kernel<<<128, 256, 0, stream>>>(bias_ws);

    int B = in_sizes[0] / 49152;   // windows
    win_attn_kernel<<<B * 2, 256, 0, stream>>>(qkv, bias_ws, (float*)d_out);
}

// Round 9
// 130.199 us; speedup vs baseline: 1.1426x; 1.1426x over previous
//
#include <hip/hip_runtime.h>
#include <hip/hip_bf16.h>
#include <string.h>

#define NTOK 64
#define HEADS 8
#define SKV 136   // LDS row stride (ushorts) = 272 B: 16B-aligned rows, 8-start-bank spread

typedef __attribute__((ext_vector_type(4))) float f32x4;
typedef __attribute__((ext_vector_type(2))) unsigned int u32x2;
typedef __attribute__((ext_vector_type(4))) unsigned int u32x4;
typedef __attribute__((ext_vector_type(8))) short bf16x8;

__device__ float g_bias225[225 * 8];   // overwritten fully every launch (deterministic)

// packed f32x2 -> bf16x2 (RNE) -- v_cvt_pk_bf16_f32
__device__ __forceinline__ unsigned int cvt2(float a, float b) {
    __hip_bfloat162 h = __float22bfloat162_rn(float2{a, b});
    unsigned int r;
    memcpy(&r, &h, 4);
    return r;
}

// Stage 1: MLP over the 225 distinct relative positions. One wave per pair.
__global__ __launch_bounds__(64) void mlp_pairs_kernel(
    const float* __restrict__ w1, const float* __restrict__ b1,
    const float* __restrict__ w2, const float* __restrict__ b2)
{
    int pair = blockIdx.x;
    int lane = threadIdx.x;
    int dy = pair / 15 - 7;
    int dx = pair % 15 - 7;
    float fy = copysignf(log1pf(fabsf((float)dy)), (float)dy);
    float fx = copysignf(log1pf(fabsf((float)dx)), (float)dx);
    int h = lane & 7;
    int j0 = lane >> 3;
    float acc = 0.0f;
    #pragma unroll 4
    for (int i = 0; i < 32; ++i) {
        int j = j0 + 8 * i;
        float t = fy * w1[j] + fx * w1[256 + j] + b1[j];
        float ge = 0.5f * t * (1.0f + erff(t * 0.70710678118654752f)); // exact GELU
        acc = fmaf(ge, w2[j * HEADS + h], acc);
    }
    acc += __shfl_xor(acc, 8, 64);
    acc += __shfl_xor(acc, 16, 64);
    acc += __shfl_xor(acc, 32, 64);
    if (lane < 8)
        g_bias225[pair * 8 + lane] = (acc + b2[lane]) * 1.44269504088896341f; // fold log2(e)
}

// Stage 2: scatter bias225 -> fragment-layout table
// bias_ws[h][mt][nt][lane][r] = log2e * bias[h][n][m],
//   m = mt*16 + (lane>>4)*4 + r (S^T C-frag row), n = nt*16 + (lane&15) (col)
__global__ __launch_bounds__(256) void bias_scatter_kernel(float* __restrict__ bias_ws)
{
    int idx = blockIdx.x * 256 + threadIdx.x;   // 32768 total
    int r  = idx & 3;
    int l  = (idx >> 2) & 63;
    int nt = (idx >> 8) & 3;
    int mt = (idx >> 10) & 3;
    int h  = idx >> 12;
    int n = nt * 16 + (l & 15);
    int m = mt * 16 + (l >> 4) * 4 + r;
    int pair = ((n >> 3) - (m >> 3) + 7) * 15 + ((n & 7) - (m & 7) + 7);
    bias_ws[idx] = g_bias225[pair * 8 + h];
}

// Block = 4 heads of one window (blockIdx = window*2 + half). Wave w -> head half*4+w.
// K,V staged block-cooperatively: 512-B contiguous segments per wave-instruction
// (vs 16x64B scattered), frag reads from LDS. Q direct per strip. P dbuf + fence (proven).
__global__ __launch_bounds__(256, 4) void win_attn_kernel(
    const float* __restrict__ qkv,
    const float* __restrict__ bias_ws,
    float* __restrict__ out)
{
    __shared__ __align__(16) unsigned short lds_k[64 * SKV];   // 17408 B
    __shared__ __align__(16) unsigned short lds_v[64 * SKV];   // 17408 B
    __shared__ __align__(16) unsigned short lds_p[4][2][16][72]; // 18432 B
    const int tid = threadIdx.x;
    const int w = tid >> 6;
    const int l = tid & 63;
    const int c = l & 15;
    const int g = l >> 4;
    const int half = blockIdx.x & 1;
    const int b = blockIdx.x >> 1;
    const int h = half * 4 + w;                      // this wave's head
    const float* wbase = qkv + (size_t)b * (NTOK * 768);
    const float QS = 0.176776695296636893f * 1.44269504088896341f; // scale * log2(e)

    // ---- block-cooperative staging of K,V (4-head slices, bf16) ----
    // thread tid: rows i*8 + (tid>>5), float-cols (tid&31)*4 .. +3  -> 512-B segments/wave-instr
    {
        const int srow0 = tid >> 5;
        const int scol  = (tid & 31) * 4;
        #pragma unroll
        for (int i = 0; i < 8; ++i) {
            int row = i * 8 + srow0;
            const float* pr = wbase + (size_t)row * 768 + half * 128 + scol;
            f32x4 kk = *(const f32x4*)(pr + 256);
            f32x4 vv = *(const f32x4*)(pr + 512);
            u32x2 kw = {cvt2(kk[0], kk[1]), cvt2(kk[2], kk[3])};
            u32x2 vw = {cvt2(vv[0], vv[1]), cvt2(vv[2], vv[3])};
            *(u32x2*)(lds_k + row * SKV + scol) = kw;   // byte row*272 + scol*2 (8B-aligned)
            *(u32x2*)(lds_v + row * SKV + scol) = vw;
        }
    }
    __syncthreads();

    // ---- K A-frags from LDS: b128, 16B-aligned, 8-cycle-minimum bank pattern ----
    bf16x8 kf[4];
    #pragma unroll
    for (int t = 0; t < 4; ++t)
        kf[t] = *(const bf16x8*)(lds_k + (t * 16 + c) * SKV + w * 32 + g * 8);

    // ---- V^T A-frags: column reads (u16; 4-way over g, once per wave) ----
    bf16x8 vf[2][2];
    #pragma unroll
    for (int ks = 0; ks < 2; ++ks)
        #pragma unroll
        for (int dt = 0; dt < 2; ++dt) {
            bf16x8 v;
            #pragma unroll
            for (int j = 0; j < 8; ++j)
                v[j] = (short)lds_v[(ks * 32 + g * 8 + j) * SKV + w * 32 + dt * 16 + c];
            vf[ks][dt] = v;
        }

    // Q strip 0 raw (direct; per-strip prefetch below)
    const float* qb = wbase + h * 32;
    f32x4 qraw0, qraw1;
    {
        const float* pq = qb + (size_t)c * 768 + g * 8;
        qraw0 = *(const f32x4*)(pq);
        qraw1 = *(const f32x4*)(pq + 4);
    }

    float* ob = out + (size_t)b * (NTOK * 256) + h * 32;

    // ---- strip loop over n (nt): S^T strip -> exp2 -> P -> O^T strip ----
    #pragma unroll
    for (int nt = 0; nt < 4; ++nt) {
        bf16x8 qf;
        {
            u32x4 qq = {cvt2(qraw0[0] * QS, qraw0[1] * QS), cvt2(qraw0[2] * QS, qraw0[3] * QS),
                        cvt2(qraw1[0] * QS, qraw1[1] * QS), cvt2(qraw1[2] * QS, qraw1[3] * QS)};
            memcpy(&qf, &qq, 16);
        }

        // S^T strip = K.Q^T seeded with bias frags (C-operand; L2-resident table)
        f32x4 acc[4];
        {
            const f32x4* bw = (const f32x4*)(bias_ws) + ((size_t)h * 16 + nt) * 64 + l;
            #pragma unroll
            for (int mt = 0; mt < 4; ++mt)
                acc[mt] = bw[mt * 256];
        }
        #pragma unroll
        for (int mt = 0; mt < 4; ++mt)
            acc[mt] = __builtin_amdgcn_mfma_f32_16x16x32_bf16(kf[mt], qf, acc[mt], 0, 0, 0);

        // prefetch next strip's Q while MFMAs run
        if (nt < 3) {
            const float* pq = qb + (size_t)((nt + 1) * 16 + c) * 768 + g * 8;
            qraw0 = *(const f32x4*)(pq);
            qraw1 = *(const f32x4*)(pq + 4);
        }

        // softmax numerators, no max-subtract (scores bounded in log2 units; f32-safe;
        // identical after normalization)
        float s = 0.0f;
        #pragma unroll
        for (int mt = 0; mt < 4; ++mt)
            #pragma unroll
            for (int r = 0; r < 4; ++r) {
                float p = __builtin_amdgcn_exp2f(acc[mt][r]);
                acc[mt][r] = p;
                s += p;
            }

        // P strip (bf16, [n][m]) -> LDS (packed cvt + b64 writes, double-buffered)
        unsigned short (*P)[72] = lds_p[w][nt & 1];
        #pragma unroll
        for (int mt = 0; mt < 4; ++mt) {
            unsigned int w0 = cvt2(acc[mt][0], acc[mt][1]);
            unsigned int w1 = cvt2(acc[mt][2], acc[mt][3]);
            *(u32x2*)(&P[c][mt * 16 + g * 4]) = (u32x2){w0, w1};
        }

        // cross-lane sum finish + rcp (overlaps the fence drain)
        s += __shfl_xor(s, 16, 64);
        s += __shfl_xor(s, 32, 64);
        float iv = __builtin_amdgcn_rcpf(s);

        // order: P ds_writes visible before cross-lane ds_reads
        __threadfence_block();

        // O^T strip = V^T . P^T
        f32x4 o[2];
        o[0] = (f32x4){0.f, 0.f, 0.f, 0.f};
        o[1] = (f32x4){0.f, 0.f, 0.f, 0.f};
        #pragma unroll
        for (int ks = 0; ks < 2; ++ks) {
            bf16x8 pb = *(const bf16x8*)(&P[c][ks * 32 + g * 8]);
            #pragma unroll
            for (int dt = 0; dt < 2; ++dt)
                o[dt] = __builtin_amdgcn_mfma_f32_16x16x32_bf16(vf[ks][dt], pb, o[dt], 0, 0, 0);
        }

        // normalize + store (4 consecutive d per reg -> dwordx4)
        #pragma unroll
        for (int dt = 0; dt < 2; ++dt) {
            f32x4 val;
            #pragma unroll
            for (int r = 0; r < 4; ++r)
                val[r] = o[dt][r] * iv;
            *(f32x4*)(ob + (size_t)(nt * 16 + c) * 256 + dt * 16 + g * 4) = val;
        }
    }
}

extern "C" void kernel_launch(void* const* d_in, const int* in_sizes, int n_in,
                              void* d_out, int out_size, void* d_ws, size_t ws_size,
                              hipStream_t stream) {
    const float* qkv = (const float*)d_in[0];
    const float* w1  = (const float*)d_in[1];
    const float* b1  = (const float*)d_in[2];
    const float* w2  = (const float*)d_in[3];
    const float* b2  = (const float*)d_in[4];
    float* bias_ws = (float*)d_ws;   // 32768 floats = 128 KiB (proven size)

    mlp_pairs_kernel<<<225, 64, 0, stream>>>(w1, b1, w2, b2);
    bias_scatter_kernel<<<128, 256, 0, stream>>>(bias_ws);

    int B = in_sizes[0] / 49152;   // windows
    win_attn_kernel<<<B * 2, 256, 0, stream>>>(qkv, bias_ws, (float*)d_out);
}

// Round 10
// 124.348 us; speedup vs baseline: 1.1964x; 1.0471x over previous
//
#include <hip/hip_runtime.h>
#include <hip/hip_bf16.h>
#include <string.h>

#define NTOK 64
#define HEADS 8
#define SKV 136   // K/V LDS row stride (ushorts) = 272 B
#define SO  132   // O-stage row stride (floats) = 528 B -> 2-way-free banks

typedef __attribute__((ext_vector_type(4))) float f32x4;
typedef __attribute__((ext_vector_type(2))) unsigned int u32x2;
typedef __attribute__((ext_vector_type(4))) unsigned int u32x4;
typedef __attribute__((ext_vector_type(8))) short bf16x8;

__device__ float g_bias225[225 * 8];   // overwritten fully every launch (deterministic)

// packed f32x2 -> bf16x2 (RNE) -- v_cvt_pk_bf16_f32
__device__ __forceinline__ unsigned int cvt2(float a, float b) {
    __hip_bfloat162 h = __float22bfloat162_rn(float2{a, b});
    unsigned int r;
    memcpy(&r, &h, 4);
    return r;
}

// Stage 1: MLP over the 225 distinct relative positions. One wave per pair.
__global__ __launch_bounds__(64) void mlp_pairs_kernel(
    const float* __restrict__ w1, const float* __restrict__ b1,
    const float* __restrict__ w2, const float* __restrict__ b2)
{
    int pair = blockIdx.x;
    int lane = threadIdx.x;
    int dy = pair / 15 - 7;
    int dx = pair % 15 - 7;
    float fy = copysignf(log1pf(fabsf((float)dy)), (float)dy);
    float fx = copysignf(log1pf(fabsf((float)dx)), (float)dx);
    int h = lane & 7;
    int j0 = lane >> 3;
    float acc = 0.0f;
    #pragma unroll 4
    for (int i = 0; i < 32; ++i) {
        int j = j0 + 8 * i;
        float t = fy * w1[j] + fx * w1[256 + j] + b1[j];
        float ge = 0.5f * t * (1.0f + erff(t * 0.70710678118654752f)); // exact GELU
        acc = fmaf(ge, w2[j * HEADS + h], acc);
    }
    acc += __shfl_xor(acc, 8, 64);
    acc += __shfl_xor(acc, 16, 64);
    acc += __shfl_xor(acc, 32, 64);
    if (lane < 8)
        g_bias225[pair * 8 + lane] = (acc + b2[lane]) * 1.44269504088896341f; // fold log2(e)
}

// Stage 2: scatter bias225 -> fragment-layout table
__global__ __launch_bounds__(256) void bias_scatter_kernel(float* __restrict__ bias_ws)
{
    int idx = blockIdx.x * 256 + threadIdx.x;   // 32768 total
    int r  = idx & 3;
    int l  = (idx >> 2) & 63;
    int nt = (idx >> 8) & 3;
    int mt = (idx >> 10) & 3;
    int h  = idx >> 12;
    int n = nt * 16 + (l & 15);
    int m = mt * 16 + (l >> 4) * 4 + r;
    int pair = ((n >> 3) - (m >> 3) + 7) * 15 + ((n & 7) - (m & 7) + 7);
    bias_ws[idx] = g_bias225[pair * 8 + h];
}

// Block = 4 heads of one window. K,V staged block-cooperatively (512-B segments);
// O accumulated in LDS (overlaying dead K/V region) and stored block-cooperatively.
__global__ __launch_bounds__(256, 4) void win_attn_kernel(
    const float* __restrict__ qkv,
    const float* __restrict__ bias_ws,
    float* __restrict__ out)
{
    // layout: [0, 17408) K stage | [17408, 34816) V stage | [34816, 53248) P dbuf
    //         O stage f32 [64][SO] (33792 B) overlays K+V after frags are register-resident
    __shared__ __align__(16) unsigned char lds_all[53248];
    unsigned short* lds_k = (unsigned short*)lds_all;
    unsigned short* lds_v = (unsigned short*)(lds_all + 17408);
    unsigned short (*lds_p)[16][72] = (unsigned short (*)[16][72])(lds_all + 34816 + (threadIdx.x >> 6) * 4608);
    float* ostage = (float*)lds_all;

    const int tid = threadIdx.x;
    const int w = tid >> 6;
    const int l = tid & 63;
    const int c = l & 15;
    const int g = l >> 4;
    const int half = blockIdx.x & 1;
    const int b = blockIdx.x >> 1;
    const int h = half * 4 + w;                      // this wave's head
    const float* wbase = qkv + (size_t)b * (NTOK * 768);
    const float QS = 0.176776695296636893f * 1.44269504088896341f; // scale * log2(e)

    // ---- block-cooperative staging of K,V (4-head slices, bf16): 512-B segments/instr ----
    {
        const int srow0 = tid >> 5;
        const int scol  = (tid & 31) * 4;
        #pragma unroll
        for (int i = 0; i < 8; ++i) {
            int row = i * 8 + srow0;
            const float* pr = wbase + (size_t)row * 768 + half * 128 + scol;
            f32x4 kk = *(const f32x4*)(pr + 256);
            f32x4 vv = *(const f32x4*)(pr + 512);
            u32x2 kw = {cvt2(kk[0], kk[1]), cvt2(kk[2], kk[3])};
            u32x2 vw = {cvt2(vv[0], vv[1]), cvt2(vv[2], vv[3])};
            *(u32x2*)(lds_k + row * SKV + scol) = kw;
            *(u32x2*)(lds_v + row * SKV + scol) = vw;
        }
    }
    __syncthreads();

    // ---- K A-frags from LDS (b128) ----
    bf16x8 kf[4];
    #pragma unroll
    for (int t = 0; t < 4; ++t)
        kf[t] = *(const bf16x8*)(lds_k + (t * 16 + c) * SKV + w * 32 + g * 8);

    // ---- V^T A-frags: column reads (u16, once per wave) ----
    bf16x8 vf[2][2];
    #pragma unroll
    for (int ks = 0; ks < 2; ++ks)
        #pragma unroll
        for (int dt = 0; dt < 2; ++dt) {
            bf16x8 v;
            #pragma unroll
            for (int j = 0; j < 8; ++j)
                v[j] = (short)lds_v[(ks * 32 + g * 8 + j) * SKV + w * 32 + dt * 16 + c];
            vf[ks][dt] = v;
        }
    __syncthreads();   // K/V region now dead -> safe to overlay with O stage

    // Q strip 0 raw (direct; per-strip prefetch below)
    const float* qb = wbase + h * 32;
    f32x4 qraw0, qraw1;
    {
        const float* pq = qb + (size_t)c * 768 + g * 8;
        qraw0 = *(const f32x4*)(pq);
        qraw1 = *(const f32x4*)(pq + 4);
    }

    // ---- strip loop over n (nt): S^T strip -> exp2 -> P -> O^T strip -> LDS O-stage ----
    #pragma unroll
    for (int nt = 0; nt < 4; ++nt) {
        bf16x8 qf;
        {
            u32x4 qq = {cvt2(qraw0[0] * QS, qraw0[1] * QS), cvt2(qraw0[2] * QS, qraw0[3] * QS),
                        cvt2(qraw1[0] * QS, qraw1[1] * QS), cvt2(qraw1[2] * QS, qraw1[3] * QS)};
            memcpy(&qf, &qq, 16);
        }

        // S^T strip = K.Q^T seeded with bias frags (C-operand; L2-resident table)
        f32x4 acc[4];
        {
            const f32x4* bw = (const f32x4*)(bias_ws) + ((size_t)h * 16 + nt) * 64 + l;
            #pragma unroll
            for (int mt = 0; mt < 4; ++mt)
                acc[mt] = bw[mt * 256];
        }
        #pragma unroll
        for (int mt = 0; mt < 4; ++mt)
            acc[mt] = __builtin_amdgcn_mfma_f32_16x16x32_bf16(kf[mt], qf, acc[mt], 0, 0, 0);

        // prefetch next strip's Q while MFMAs run
        if (nt < 3) {
            const float* pq = qb + (size_t)((nt + 1) * 16 + c) * 768 + g * 8;
            qraw0 = *(const f32x4*)(pq);
            qraw1 = *(const f32x4*)(pq + 4);
        }

        // softmax numerators, no max-subtract (bounded log2-unit scores; f32-safe)
        float s = 0.0f;
        #pragma unroll
        for (int mt = 0; mt < 4; ++mt)
            #pragma unroll
            for (int r = 0; r < 4; ++r) {
                float p = __builtin_amdgcn_exp2f(acc[mt][r]);
                acc[mt][r] = p;
                s += p;
            }

        // P strip (bf16, [n][m]) -> LDS (packed cvt + b64 writes, double-buffered)
        unsigned short (*P)[72] = lds_p[nt & 1];
        #pragma unroll
        for (int mt = 0; mt < 4; ++mt) {
            unsigned int w0 = cvt2(acc[mt][0], acc[mt][1]);
            unsigned int w1 = cvt2(acc[mt][2], acc[mt][3]);
            *(u32x2*)(&P[c][mt * 16 + g * 4]) = (u32x2){w0, w1};
        }

        // cross-lane sum finish + rcp (overlaps the fence drain)
        s += __shfl_xor(s, 16, 64);
        s += __shfl_xor(s, 32, 64);
        float iv = __builtin_amdgcn_rcpf(s);

        // order: P ds_writes visible before cross-lane ds_reads
        __threadfence_block();

        // O^T strip = V^T . P^T
        f32x4 o[2];
        o[0] = (f32x4){0.f, 0.f, 0.f, 0.f};
        o[1] = (f32x4){0.f, 0.f, 0.f, 0.f};
        #pragma unroll
        for (int ks = 0; ks < 2; ++ks) {
            bf16x8 pb = *(const bf16x8*)(&P[c][ks * 32 + g * 8]);
            #pragma unroll
            for (int dt = 0; dt < 2; ++dt)
                o[dt] = __builtin_amdgcn_mfma_f32_16x16x32_bf16(vf[ks][dt], pb, o[dt], 0, 0, 0);
        }

        // normalize + write to LDS O-stage [64][SO] f32 (col ranges disjoint per wave)
        #pragma unroll
        for (int dt = 0; dt < 2; ++dt) {
            f32x4 val;
            #pragma unroll
            for (int r = 0; r < 4; ++r)
                val[r] = o[dt][r] * iv;
            *(f32x4*)(ostage + (nt * 16 + c) * SO + w * 32 + dt * 16 + g * 4) = val;
        }
    }
    __syncthreads();

    // ---- block-cooperative store: per instr 2 rows x 512 B contiguous ----
    {
        float* ob = out + (size_t)b * (NTOK * 256) + half * 128;
        const int srow0 = tid >> 5;
        const int scol  = (tid & 31) * 4;
        #pragma unroll
        for (int i = 0; i < 8; ++i) {
            int row = i * 8 + srow0;
            f32x4 val = *(const f32x4*)(ostage + row * SO + scol);
            *(f32x4*)(ob + (size_t)row * 256 + scol) = val;
        }
    }
}

extern "C" void kernel_launch(void* const* d_in, const int* in_sizes, int n_in,
                              void* d_out, int out_size, void* d_ws, size_t ws_size,
                              hipStream_t stream) {
    const float* qkv = (const float*)d_in[0];
    const float* w1  = (const float*)d_in[1];
    const float* b1  = (const float*)d_in[2];
    const float* w2  = (const float*)d_in[3];
    const float* b2  = (const float*)d_in[4];
    float* bias_ws = (float*)d_ws;   // 32768 floats = 128 KiB (proven size)

    mlp_pairs_kernel<<<225, 64, 0, stream>>>(w1, b1, w2, b2);
    bias_scatter_kernel<<<128, 256, 0, stream>>>(bias_ws);

    int B = in_sizes[0] / 49152;   // windows
    win_attn_kernel<<<B * 2, 256, 0, stream>>>(qkv, bias_ws, (float*)d_out);
}